// Round 12
// baseline (161.588 us; speedup 1.0000x reference)
//
#include <hip/hip_runtime.h>
#include <hip/hip_bf16.h>

#define BLK 256
#define SPLITS 25                 // scan splits (grid.x)
#define FPS 64                    // frags per split (divisible by 4)
#define FRTOT (SPLITS * FPS)      // 1600 B-fragments; slots = 51200
#define NSLOT (FRTOT * 32)        // 51200 scan slots (>= N, padded w/ sentinel)
#define THRESH 0.1f
#define KEY_MAX 0xFFFFFFFFu
#define ONE_BF ((unsigned short)0x3F80)  // bf16(1.0)

typedef __attribute__((ext_vector_type(8))) short short8;
typedef __attribute__((ext_vector_type(16))) float floatx16;

__device__ __forceinline__ unsigned short f2bf(float x) {
    unsigned u = __float_as_uint(x);
    unsigned r = u + 0x7FFFu + ((u >> 16) & 1u);
    return (unsigned short)(r >> 16);
}
__device__ __forceinline__ float bf2f(unsigned short h) {
    return __uint_as_float(((unsigned)h) << 16);
}

// Order-preserving float->uint map: min in key space == min in float space.
__device__ __forceinline__ unsigned f2key(float f) {
    unsigned b = __float_as_uint(f);
    return (b & 0x80000000u) ? ~b : (b | 0x80000000u);
}
__device__ __forceinline__ float key2f(unsigned k) {
    return __uint_as_float((k & 0x80000000u) ? (k & 0x7FFFFFFFu) : ~k);
}

// min with DPP row_ror permute (2 VALU). CTRL: 0x120+N = row_ror:N (16-lane rows).
template <int CTRL>
__device__ __forceinline__ float dpp_ror_min(float v) {
    const int i = __float_as_int(v);
    const int p = __builtin_amdgcn_update_dpp(i, i, CTRL, 0xF, 0xF, false);
    return fminf(v, __int_as_float(p));
}

// Prep: pack scan into global B-fragments (split-bf16, K=16); init gmin,
// done-counter. B k-dims (s' = -2s): [sxh,sxl,sxh,sxl, syh,syl,syh,syl,
// szh,szl,szh,szl, 1,1, s2h,s2l]; lane L of consumer reads fragbuf[f*64+L].
__global__ __launch_bounds__(BLK) void pdl_prep(const float* __restrict__ scan,
                                                uint4* __restrict__ fragbuf,
                                                unsigned* __restrict__ gmin,
                                                unsigned* __restrict__ done,
                                                int N, int Mpad) {
    const int n = blockIdx.x * BLK + threadIdx.x;
    if (n == 0) done[0] = 0u;
    if (n < Mpad) gmin[n] = KEY_MAX;
    if (n >= NSLOT) return;

    unsigned short k[16];
    if (n < N) {
        const float x = scan[3 * n + 0], y = scan[3 * n + 1], z = scan[3 * n + 2];
        const float s2 = fmaf(x, x, fmaf(y, y, z * z));
        const float cx = -2.0f * x, cy = -2.0f * y, cz = -2.0f * z;
        const unsigned short xh = f2bf(cx); const unsigned short xl = f2bf(cx - bf2f(xh));
        const unsigned short yh = f2bf(cy); const unsigned short yl = f2bf(cy - bf2f(yh));
        const unsigned short zh = f2bf(cz); const unsigned short zl = f2bf(cz - bf2f(zh));
        const unsigned short wh = f2bf(s2); const unsigned short wl = f2bf(s2 - bf2f(wh));
        k[0] = xh; k[1] = xl; k[2] = xh; k[3] = xl;
        k[4] = yh; k[5] = yl; k[6] = yh; k[7] = yl;
        k[8] = zh; k[9] = zl; k[10] = zh; k[11] = zl;
        k[12] = ONE_BF; k[13] = ONE_BF;
        k[14] = wh; k[15] = wl;
    } else {  // padded slot: d2 = t2 + 1e30 -> never the min
#pragma unroll
        for (int i = 0; i < 16; ++i) k[i] = 0;
        k[12] = ONE_BF; k[13] = ONE_BF;
        k[14] = f2bf(1e30f); k[15] = 0;
    }

    const int g = n >> 5, c = n & 31;
    uint4 lo, hi;
    lo.x = (unsigned)k[0] | ((unsigned)k[1] << 16);
    lo.y = (unsigned)k[2] | ((unsigned)k[3] << 16);
    lo.z = (unsigned)k[4] | ((unsigned)k[5] << 16);
    lo.w = (unsigned)k[6] | ((unsigned)k[7] << 16);
    hi.x = (unsigned)k[8] | ((unsigned)k[9] << 16);
    hi.y = (unsigned)k[10] | ((unsigned)k[11] << 16);
    hi.z = (unsigned)k[12] | ((unsigned)k[13] << 16);
    hi.w = (unsigned)k[14] | ((unsigned)k[15] << 16);
    fragbuf[(size_t)g * 64 + c] = lo;        // lanes 0-31: k = 0..7
    fragbuf[(size_t)g * 64 + 32 + c] = hi;   // lanes 32-63: k = 8..15
}

// Main (final fused): no LDS tile, no mid-kernel barrier. Each wave: 1 A-frag
// (32 templates) vs 64 B-frags read global->VGPR with 4-DEEP register
// prefetch (4 loads in flight -> partial vmcnt waits cover ~200cyc L2 lat).
// After atomicMin stores, blocks count down; last block re-reads gmin with
// device-scope atomic reads, thresholds, reduces, stores out[0].
__global__ __launch_bounds__(BLK, 4) void pdl_main(const float* __restrict__ tmpl,
                                                   const uint4* __restrict__ fragbuf,
                                                   unsigned* __restrict__ gmin,
                                                   unsigned* __restrict__ done,
                                                   float* __restrict__ out,
                                                   int M, int nBlocks) {
    const int tid = threadIdx.x;
    const int wave = tid >> 6, lane = tid & 63;

    // A-frag: k-dims = [txh,txh,txl,txl, tyh,tyh,tyl,tyl] (lanes 0-31),
    //                  [tzh,tzh,tzl,tzl, t2h,t2l, 1,1]    (lanes 32-63).
    const int mbase = (blockIdx.y * 4 + wave) * 32;
    short8 A;
    {
        int m = mbase + (lane & 31);
        if (m > M - 1) m = M - 1;  // clamped dup row; excluded in final (m<M)
        const float x = tmpl[3 * m + 0], y = tmpl[3 * m + 1], z = tmpl[3 * m + 2];
        const float t2 = fmaf(x, x, fmaf(y, y, z * z));
        const unsigned short xh = f2bf(x); const unsigned short xl = f2bf(x - bf2f(xh));
        const unsigned short yh = f2bf(y); const unsigned short yl = f2bf(y - bf2f(yh));
        const unsigned short zh = f2bf(z); const unsigned short zl = f2bf(z - bf2f(zh));
        const unsigned short wh = f2bf(t2); const unsigned short wl = f2bf(t2 - bf2f(wh));
        const bool hi = (lane >= 32);
        A[0] = (short)(hi ? zh : xh);
        A[1] = (short)(hi ? zh : xh);
        A[2] = (short)(hi ? zl : xl);
        A[3] = (short)(hi ? zl : xl);
        A[4] = (short)(hi ? wh : yh);
        A[5] = (short)(hi ? wl : yh);
        A[6] = (short)(hi ? ONE_BF : yl);
        A[7] = (short)(hi ? ONE_BF : yl);
    }

    floatx16 mn, zacc;
#pragma unroll
    for (int r = 0; r < 16; ++r) { mn[r] = 3e30f; zacc[r] = 0.0f; }

    const uint4* fb = fragbuf + (size_t)(blockIdx.x * FPS) * 64 + lane;

    union U { uint4 u; short8 s; };
    // 4-deep prefetch (over-reads 4 frags past split end; fragbuf padded).
    uint4 p0 = fb[0 * 64], p1 = fb[1 * 64], p2 = fb[2 * 64], p3 = fb[3 * 64];
#pragma unroll 1
    for (int f = 0; f < FPS; f += 4) {
        U c0, c1, c2, c3;
        c0.u = p0; c1.u = p1; c2.u = p2; c3.u = p3;
        p0 = fb[(size_t)(f + 4) * 64];
        p1 = fb[(size_t)(f + 5) * 64];
        p2 = fb[(size_t)(f + 6) * 64];
        p3 = fb[(size_t)(f + 7) * 64];
        const floatx16 d0 = __builtin_amdgcn_mfma_f32_32x32x16_bf16(A, c0.s, zacc, 0, 0, 0);
        const floatx16 d1 = __builtin_amdgcn_mfma_f32_32x32x16_bf16(A, c1.s, zacc, 0, 0, 0);
#pragma unroll
        for (int r = 0; r < 16; ++r)
            mn[r] = fminf(fminf(d0[r], d1[r]), mn[r]);  // -> v_min3_f32
        const floatx16 d2 = __builtin_amdgcn_mfma_f32_32x32x16_bf16(A, c2.s, zacc, 0, 0, 0);
        const floatx16 d3 = __builtin_amdgcn_mfma_f32_32x32x16_bf16(A, c3.s, zacc, 0, 0, 0);
#pragma unroll
        for (int r = 0; r < 16; ++r)
            mn[r] = fminf(fminf(d2[r], d3[r]), mn[r]);
    }

    // Epilogue: min over 32 scan-cols per 32-lane half. C/D layout:
    // col=lane&31, row=(r&3)+8*(r>>2)+4*(lane>>5)  [m74/m101].
#pragma unroll
    for (int r = 0; r < 16; ++r) {
        float v = mn[r];
        v = dpp_ror_min<0x128>(v);
        v = dpp_ror_min<0x124>(v);
        v = dpp_ror_min<0x122>(v);
        v = dpp_ror_min<0x121>(v);
        const int sw = __builtin_amdgcn_ds_swizzle(__float_as_int(v), 0x401F);
        v = fminf(v, __int_as_float(sw));  // xor lane^16 within 32-group
        if ((lane & 31) == 0) {
            const int row = (r & 3) + 8 * (r >> 2) + ((lane >> 5) << 2);
            atomicMin(&gmin[mbase + row], f2key(v));
        }
    }

    // ---- fused final: last-finished block reduces gmin -> out[0] ----
    __shared__ unsigned doneRank;
    __shared__ float ls[BLK / 64];
    __threadfence();  // release gmin atomics device-wide
    if (tid == 0) doneRank = atomicAdd(done, 1u);
    __syncthreads();
    if (doneRank == (unsigned)(nBlocks - 1)) {
        float s = 0.0f;
        for (int m = tid; m < M; m += BLK) {
            // atomicMin(p, MAX) = device-scope coherent read, no modification.
            const float v = key2f(atomicMin(&gmin[m], KEY_MAX));
            if (v < THRESH) s += v;
        }
#pragma unroll
        for (int off = 32; off > 0; off >>= 1) s += __shfl_down(s, off, 64);
        if (lane == 0) ls[wave] = s;
        __syncthreads();
        if (tid == 0) {
            float t = 0.0f;
#pragma unroll
            for (int i = 0; i < BLK / 64; ++i) t += ls[i];
            out[0] = t;
        }
    }
}

extern "C" void kernel_launch(void* const* d_in, const int* in_sizes, int n_in,
                              void* d_out, int out_size, void* d_ws, size_t ws_size,
                              hipStream_t stream) {
    const float* scan = (const float*)d_in[0];   // [N,3] fp32
    const float* tmpl = (const float*)d_in[1];   // [M,3] fp32
    float* out = (float*)d_out;                  // scalar fp32

    const int N = in_sizes[0] / 3;               // 50000
    const int M = in_sizes[1] / 3;               // 6890

    const int tGroups = (M + 127) / 128;         // 54 blocks of 128 templates
    const int Mpad = tGroups * 128;              // 6912 (covers clamped-dup rows)

    // ws: gmin [0, 32KB) ; done at 32KB ; fragbuf at 64KB ((FRTOT+4) x 1KB)
    unsigned* gmin = (unsigned*)d_ws;
    unsigned* done = (unsigned*)((char*)d_ws + 32768);
    uint4* fragbuf = (uint4*)((char*)d_ws + 65536);

    pdl_prep<<<(NSLOT + BLK - 1) / BLK, BLK, 0, stream>>>(scan, fragbuf, gmin,
                                                          done, N, Mpad);

    dim3 grid(SPLITS, tGroups);
    pdl_main<<<grid, BLK, 0, stream>>>(tmpl, fragbuf, gmin, done, out, M,
                                       SPLITS * tGroups);
}

// Round 13
// 81.036 us; speedup vs baseline: 1.9940x; 1.9940x over previous
//
#include <hip/hip_runtime.h>
#include <hip/hip_bf16.h>

#define BLK 256
#define SPLITS 25                 // scan splits (grid.x)
#define FPS 64                    // frags per split (even, for unroll-2)
#define FRTOT (SPLITS * FPS)      // 1600 B-fragments; slots = 51200
#define NSLOT (FRTOT * 32)        // 51200 scan slots (>= N, padded w/ sentinel)
#define THRESH 0.1f
#define KEY_MAX 0xFFFFFFFFu
#define ONE_BF ((unsigned short)0x3F80)  // bf16(1.0)

typedef __attribute__((ext_vector_type(8))) short short8;
typedef __attribute__((ext_vector_type(16))) float floatx16;

__device__ __forceinline__ unsigned short f2bf(float x) {
    unsigned u = __float_as_uint(x);
    unsigned r = u + 0x7FFFu + ((u >> 16) & 1u);
    return (unsigned short)(r >> 16);
}
__device__ __forceinline__ float bf2f(unsigned short h) {
    return __uint_as_float(((unsigned)h) << 16);
}

// Order-preserving float->uint map: min in key space == min in float space.
__device__ __forceinline__ unsigned f2key(float f) {
    unsigned b = __float_as_uint(f);
    return (b & 0x80000000u) ? ~b : (b | 0x80000000u);
}
__device__ __forceinline__ float key2f(unsigned k) {
    return __uint_as_float((k & 0x80000000u) ? (k & 0x7FFFFFFFu) : ~k);
}

// min with DPP row_ror permute (2 VALU). CTRL: 0x120+N = row_ror:N (16-lane rows).
template <int CTRL>
__device__ __forceinline__ float dpp_ror_min(float v) {
    const int i = __float_as_int(v);
    const int p = __builtin_amdgcn_update_dpp(i, i, CTRL, 0xF, 0xF, false);
    return fminf(v, __int_as_float(p));
}

// Prep: pack scan into global B-fragments (split-bf16, K=16); init gmin + out.
// B k-dims (s' = -2s): [sxh,sxl,sxh,sxl, syh,syl,syh,syl, szh,szl,szh,szl,
// 1,1, s2h,s2l]; lane L of the consuming wave reads fragbuf[f*64+L].
__global__ __launch_bounds__(BLK) void pdl_prep(const float* __restrict__ scan,
                                                uint4* __restrict__ fragbuf,
                                                unsigned* __restrict__ gmin,
                                                float* __restrict__ out,
                                                int N, int Mpad) {
    const int n = blockIdx.x * BLK + threadIdx.x;
    if (n == 0) out[0] = 0.0f;
    if (n < Mpad) gmin[n] = KEY_MAX;
    if (n >= NSLOT) return;

    unsigned short k[16];
    if (n < N) {
        const float x = scan[3 * n + 0], y = scan[3 * n + 1], z = scan[3 * n + 2];
        const float s2 = fmaf(x, x, fmaf(y, y, z * z));
        const float cx = -2.0f * x, cy = -2.0f * y, cz = -2.0f * z;
        const unsigned short xh = f2bf(cx); const unsigned short xl = f2bf(cx - bf2f(xh));
        const unsigned short yh = f2bf(cy); const unsigned short yl = f2bf(cy - bf2f(yh));
        const unsigned short zh = f2bf(cz); const unsigned short zl = f2bf(cz - bf2f(zh));
        const unsigned short wh = f2bf(s2); const unsigned short wl = f2bf(s2 - bf2f(wh));
        k[0] = xh; k[1] = xl; k[2] = xh; k[3] = xl;
        k[4] = yh; k[5] = yl; k[6] = yh; k[7] = yl;
        k[8] = zh; k[9] = zl; k[10] = zh; k[11] = zl;
        k[12] = ONE_BF; k[13] = ONE_BF;
        k[14] = wh; k[15] = wl;
    } else {  // padded slot: d2 = t2 + 1e30 -> never the min
#pragma unroll
        for (int i = 0; i < 16; ++i) k[i] = 0;
        k[12] = ONE_BF; k[13] = ONE_BF;
        k[14] = f2bf(1e30f); k[15] = 0;
    }

    const int g = n >> 5, c = n & 31;
    uint4 lo, hi;
    lo.x = (unsigned)k[0] | ((unsigned)k[1] << 16);
    lo.y = (unsigned)k[2] | ((unsigned)k[3] << 16);
    lo.z = (unsigned)k[4] | ((unsigned)k[5] << 16);
    lo.w = (unsigned)k[6] | ((unsigned)k[7] << 16);
    hi.x = (unsigned)k[8] | ((unsigned)k[9] << 16);
    hi.y = (unsigned)k[10] | ((unsigned)k[11] << 16);
    hi.z = (unsigned)k[12] | ((unsigned)k[13] << 16);
    hi.w = (unsigned)k[14] | ((unsigned)k[15] << 16);
    fragbuf[(size_t)g * 64 + c] = lo;        // lanes 0-31: k = 0..7
    fragbuf[(size_t)g * 64 + 32 + c] = hi;   // lanes 32-63: k = 8..15
}

// Main: R11 structure (no LDS, no barrier, separate final) but each wave now
// carries 2 A-frags (64 templates) -> every B-frag load feeds 2 MFMAs + 32
// min3 (~160cyc compute per 16B load): 2x load-use distance at the SAME
// prefetch register count as R11. R12's fused-tail + 4-deep variant collapsed
// the allocator to VGPR=32 and tripled main; this keeps pressure ~80 VGPRs.
__global__ __launch_bounds__(BLK, 4) void pdl_main(const float* __restrict__ tmpl,
                                                   const uint4* __restrict__ fragbuf,
                                                   unsigned* __restrict__ gmin,
                                                   int M) {
    const int tid = threadIdx.x;
    const int wave = tid >> 6, lane = tid & 63;

    // A-frags: k-dims = [txh,txh,txl,txl, tyh,tyh,tyl,tyl] (lanes 0-31),
    //                   [tzh,tzh,tzl,tzl, t2h,t2l, 1,1]    (lanes 32-63).
    const int mbase = (blockIdx.y * 4 + wave) * 64;
    short8 A0, A1;
#pragma unroll
    for (int af = 0; af < 2; ++af) {
        int m = mbase + af * 32 + (lane & 31);
        if (m > M - 1) m = M - 1;  // clamped dup row; excluded in final (m<M)
        const float x = tmpl[3 * m + 0], y = tmpl[3 * m + 1], z = tmpl[3 * m + 2];
        const float t2 = fmaf(x, x, fmaf(y, y, z * z));
        const unsigned short xh = f2bf(x); const unsigned short xl = f2bf(x - bf2f(xh));
        const unsigned short yh = f2bf(y); const unsigned short yl = f2bf(y - bf2f(yh));
        const unsigned short zh = f2bf(z); const unsigned short zl = f2bf(z - bf2f(zh));
        const unsigned short wh = f2bf(t2); const unsigned short wl = f2bf(t2 - bf2f(wh));
        const bool hi = (lane >= 32);
        short8 a;
        a[0] = (short)(hi ? zh : xh);
        a[1] = (short)(hi ? zh : xh);
        a[2] = (short)(hi ? zl : xl);
        a[3] = (short)(hi ? zl : xl);
        a[4] = (short)(hi ? wh : yh);
        a[5] = (short)(hi ? wl : yh);
        a[6] = (short)(hi ? ONE_BF : yl);
        a[7] = (short)(hi ? ONE_BF : yl);
        if (af == 0) A0 = a; else A1 = a;
    }

    floatx16 mn0, mn1, zacc;
#pragma unroll
    for (int r = 0; r < 16; ++r) { mn0[r] = 3e30f; mn1[r] = 3e30f; zacc[r] = 0.0f; }

    const uint4* fb = fragbuf + (size_t)(blockIdx.x * FPS) * 64 + lane;

    union U { uint4 u; short8 s; };
    // 2-deep prefetch (as R11); over-reads 2 frags past split end (padded).
    uint4 p0 = fb[0 * 64], p1 = fb[1 * 64];
#pragma unroll 1
    for (int f = 0; f < FPS; f += 2) {
        U c0, c1;
        c0.u = p0; c1.u = p1;
        p0 = fb[(size_t)(f + 2) * 64];
        p1 = fb[(size_t)(f + 3) * 64];
        const floatx16 d00 = __builtin_amdgcn_mfma_f32_32x32x16_bf16(A0, c0.s, zacc, 0, 0, 0);
        const floatx16 d10 = __builtin_amdgcn_mfma_f32_32x32x16_bf16(A1, c0.s, zacc, 0, 0, 0);
        const floatx16 d01 = __builtin_amdgcn_mfma_f32_32x32x16_bf16(A0, c1.s, zacc, 0, 0, 0);
        const floatx16 d11 = __builtin_amdgcn_mfma_f32_32x32x16_bf16(A1, c1.s, zacc, 0, 0, 0);
#pragma unroll
        for (int r = 0; r < 16; ++r) {
            mn0[r] = fminf(fminf(d00[r], d01[r]), mn0[r]);  // -> v_min3_f32
            mn1[r] = fminf(fminf(d10[r], d11[r]), mn1[r]);
        }
    }

    // Epilogue: min over 32 scan-cols per 32-lane half. C/D layout:
    // col=lane&31, row=(r&3)+8*(r>>2)+4*(lane>>5)  [m74/m101].
#pragma unroll
    for (int af = 0; af < 2; ++af) {
#pragma unroll
        for (int r = 0; r < 16; ++r) {
            float v = (af == 0) ? mn0[r] : mn1[r];
            v = dpp_ror_min<0x128>(v);
            v = dpp_ror_min<0x124>(v);
            v = dpp_ror_min<0x122>(v);
            v = dpp_ror_min<0x121>(v);
            const int sw = __builtin_amdgcn_ds_swizzle(__float_as_int(v), 0x401F);
            v = fminf(v, __int_as_float(sw));  // xor lane^16 within 32-group
            if ((lane & 31) == 0) {
                const int row = (r & 3) + 8 * (r >> 2) + ((lane >> 5) << 2);
                atomicMin(&gmin[mbase + af * 32 + row], f2key(v));
            }
        }
    }
}

// Unmap, threshold, block-reduce, atomicAdd.
__global__ __launch_bounds__(BLK) void pdl_final(const unsigned* __restrict__ gmin,
                                                 float* __restrict__ out, int M) {
    const int m = blockIdx.x * BLK + threadIdx.x;
    float s = 0.0f;
    if (m < M) {
        const float v = key2f(gmin[m]);
        if (v < THRESH) s = v;
    }
#pragma unroll
    for (int off = 32; off > 0; off >>= 1) s += __shfl_down(s, off, 64);

    __shared__ float ls[BLK / 64];
    const int lane = threadIdx.x & 63;
    const int w = threadIdx.x >> 6;
    if (lane == 0) ls[w] = s;
    __syncthreads();
    if (threadIdx.x == 0) {
        float t = 0.0f;
#pragma unroll
        for (int i = 0; i < BLK / 64; ++i) t += ls[i];
        atomicAdd(out, t);
    }
}

extern "C" void kernel_launch(void* const* d_in, const int* in_sizes, int n_in,
                              void* d_out, int out_size, void* d_ws, size_t ws_size,
                              hipStream_t stream) {
    const float* scan = (const float*)d_in[0];   // [N,3] fp32
    const float* tmpl = (const float*)d_in[1];   // [M,3] fp32
    float* out = (float*)d_out;                  // scalar fp32

    const int N = in_sizes[0] / 3;               // 50000
    const int M = in_sizes[1] / 3;               // 6890

    const int tGroups = (M + 255) / 256;         // 27 blocks of 256 templates
    const int Mpad = tGroups * 256;              // 6912

    // ws: gmin [0, 64KB) ; fragbuf at 64KB: (FRTOT+4) frags x 1KB ~ 1.6 MB
    unsigned* gmin = (unsigned*)d_ws;
    uint4* fragbuf = (uint4*)((char*)d_ws + 65536);

    pdl_prep<<<(NSLOT + BLK - 1) / BLK, BLK, 0, stream>>>(scan, fragbuf, gmin,
                                                          out, N, Mpad);

    dim3 grid(SPLITS, tGroups);
    pdl_main<<<grid, BLK, 0, stream>>>(tmpl, fragbuf, gmin, M);

    pdl_final<<<(M + BLK - 1) / BLK, BLK, 0, stream>>>(gmin, out, M);
}